// Round 15
// baseline (52.607 us; speedup 1.0000x reference)
//
#include <hip/hip_runtime.h>
#include <hip/hip_bf16.h>

#define NS   16384
#define FKD  2048
#define CD   100
#define CP   112
#define NKC  32                  // split-K grid.y
#define PHASES 16                // (NS / NKC) / 32 rows per phase
#define EPSF 1e-8f
#define SFK  (FKD * CP)
#define NGRP (NS / 8)
#define WBUF 1024                // dwords per wave-buffer (32 rows x 32 cols)

typedef float f32x4 __attribute__((ext_vector_type(4)));
typedef short bf16x8 __attribute__((ext_vector_type(8)));
typedef unsigned uint4v __attribute__((ext_vector_type(4)));

__device__ inline unsigned short f2bf(float f) {
    unsigned int u = __float_as_uint(f);
    u += 0x7FFFu + ((u >> 16) & 1u);   // RNE; inputs finite in [0,1]
    return (unsigned short)(u >> 16);
}

__device__ __forceinline__ void gload16(const float* g, const float* l) {
    __builtin_amdgcn_global_load_lds(
        (const __attribute__((address_space(1))) void*)g,
        (__attribute__((address_space(3))) void*)l, 16, 0, 0);
}

// ---------------- prep: teacher -> bf16 fragment layout; resets tail counter ----------------
__global__ __launch_bounds__(256) void ebl_prep(
    const float* __restrict__ tp, unsigned short* __restrict__ Bp,
    unsigned* __restrict__ cnt)
{
    const int idx = blockIdx.x * 256 + threadIdx.x;     // (g, c)
    if (idx == 0) *cnt = 0;                              // reset completion counter each call
    if (idx >= NGRP * CP) return;
    const int g = idx / CP, c = idx - g * CP;
    unsigned short v[8];
    if (c < CD) {
        const float* p = tp + (size_t)g * 8 * CD + c;
        #pragma unroll
        for (int j = 0; j < 8; ++j) v[j] = f2bf(p[(size_t)j * CD]);
    } else {
        const unsigned short fill = (c == CD) ? 0x3F80 : 0;   // bf16(1.0) / 0
        #pragma unroll
        for (int j = 0; j < 8; ++j) v[j] = fill;
    }
    *reinterpret_cast<uint4*>(Bp + (size_t)idx * 8) = *reinterpret_cast<const uint4*>(v);
}

// ---------------- GEMM: wave-private 4-buffer pipeline, prefetch distance 3 ----------------
// Per wave-phase: 32 n-rows x 32 m-cols (4 KB) staged by 4 x global_load_lds(size=16):
// instr q = rows 8q..8q+7; lane l -> row l>>3, cols (l&7)*4..+3 (128B contiguous/row).
// Frag read: buf + lg*(8 rows)*32 ... af[i][j] = A[n=8lg+j][m= w*32 + i*16 + lr].
__global__ __launch_bounds__(128) void ebl_gemm(
    const float* __restrict__ mem, const unsigned short* __restrict__ Bp,
    unsigned short* __restrict__ spart)
{
    __shared__ float At[4 * 2 * WBUF];     // 4 bufs x 2 waves x 4 KB = 32 KB

    const int t  = threadIdx.x;
    const int w  = t >> 6;                 // wave 0..1 -> m cols [w*32, w*32+32)
    const int l  = t & 63;
    const int lg = l >> 4, lr = l & 15;
    const int m0 = blockIdx.x * 64;
    const int kc = blockIdx.y;
    const int n0 = kc * (PHASES * 32);
    const int gb = n0 >> 3;

    // per-lane global base for staging: row n0 + (l>>3), col m0 + w*32 + (l&7)*4
    const float* gbase = mem + (size_t)(n0 + (l >> 3)) * FKD + (m0 + w * 32 + (l & 7) * 4);

    f32x4 acc[2][7];
    #pragma unroll
    for (int i = 0; i < 2; ++i)
        #pragma unroll
        for (int nt = 0; nt < 7; ++nt) acc[i][nt] = (f32x4){0.f, 0.f, 0.f, 0.f};

    bf16x8 b0[7], b1[7];

#define SB() __builtin_amdgcn_sched_barrier(0)
#define BUFO(p) ((((p) & 3) * 2 + w) * WBUF)
#define STAGE(p) { \
    const float* gs = gbase + (size_t)(p) * 32 * FKD; \
    const int bo_ = BUFO(p); \
    _Pragma("unroll") \
    for (int q = 0; q < 4; ++q) \
        gload16(gs + (size_t)q * 8 * FKD, At + bo_ + q * 256); \
    SB(); }
#define LOADB(dst, p) { \
    const unsigned short* bq = Bp + ((size_t)(gb + (p) * 4 + lg) * CP + lr) * 8; \
    _Pragma("unroll") \
    for (int nt = 0; nt < 7; ++nt) dst[nt] = *reinterpret_cast<const bf16x8*>(bq + nt * 128); \
    SB(); }
#define WAITV(n) { asm volatile("s_waitcnt vmcnt(" #n ")" ::: "memory"); SB(); }
#define COMPUTE(p, bB) { \
    const int bo_ = BUFO(p); \
    bf16x8 af[2]; \
    _Pragma("unroll") \
    for (int i = 0; i < 2; ++i) { \
        uint4v u; \
        _Pragma("unroll") \
        for (int jj = 0; jj < 4; ++jj) { \
            float f0 = At[bo_ + ((2 * lg + (jj >> 1)) * 4 + 2 * (jj & 1))     * 32 + i * 16 + lr]; \
            float f1 = At[bo_ + ((2 * lg + (jj >> 1)) * 4 + 2 * (jj & 1) + 1) * 32 + i * 16 + lr]; \
            unsigned uu; \
            asm("v_cvt_pk_bf16_f32 %0, %1, %2" : "=v"(uu) : "v"(f0), "v"(f1)); \
            u[jj] = uu; \
        } \
        af[i] = __builtin_bit_cast(bf16x8, u); \
    } \
    SB(); \
    _Pragma("unroll") \
    for (int i = 0; i < 2; ++i) \
        _Pragma("unroll") \
        for (int nt = 0; nt < 7; ++nt) \
            acc[i][nt] = __builtin_amdgcn_mfma_f32_16x16x32_bf16(af[i], bB[nt], acc[i][nt], 0, 0, 0); }
    // NOTE frag k-map: chunk q holds rows 8q..8q+7 at bo + q*256 + (row&7)*32 + col.
    // Row n = 8*lg + j  ->  q = lg (j<8 keeps within 8-row chunk? rows per chunk = 8, q = n>>3 = lg when j<8)
    // off = lg*256 + j*32 + i*16 + lr. The expression above encodes exactly this:
    // (2*lg + (jj>>1))*4 + 2*(jj&1) (+1) ranges over j = 0..7 in pairs: (8*lg + j)*32 with j=4*(jj>>1)+2*(jj&1)(+1)
    // => pairs (0,1),(2,3),(4,5),(6,7) reordered as (0,1),(4,5),(2,3),(6,7)? verify: jj=0: j=0,1; jj=1: j=2,3 -> (2*lg)*4+2 = 8lg+2 ok wait
    // jj=1: (2*lg+0)*4 + 2 = 8*lg + 2 -> j=2,3 ✓ ; jj=2: (2*lg+1)*4+0 = 8*lg+4 -> j=4,5 ✓ ; jj=3: 8*lg+6 -> j=6,7 ✓.

    // prologue ordered so iter-0 steady-state count holds: S0, S1, B0, S2
    STAGE(0)
    STAGE(1)
    LOADB(b0, 0)
    STAGE(2)

    // main: one phase per iteration, prefetch distance 3
    for (int ph = 0; ph < PHASES - 3; ++ph) {
        LOADB(b1, ph + 1)
        STAGE(ph + 3)
        WAITV(15)                 // newer than B(ph): S(ph+2)=4 + B(ph+1)=7 + S(ph+3)=4
        COMPUTE(ph, b0)
        #pragma unroll
        for (int nt = 0; nt < 7; ++nt) b0[nt] = b1[nt];
    }
    // ph = PHASES-3
    LOADB(b1, PHASES - 2)
    WAITV(11)                     // newer than B(P-3): S(P-1)=4 + B(P-2)=7
    COMPUTE(PHASES - 3, b0)
    #pragma unroll
    for (int nt = 0; nt < 7; ++nt) b0[nt] = b1[nt];
    // ph = PHASES-2
    LOADB(b1, PHASES - 1)
    WAITV(7)                      // newer than B(P-2): B(P-1)=7
    COMPUTE(PHASES - 2, b0)
    // ph = PHASES-1
    WAITV(0)
    COMPUTE(PHASES - 1, b1)

#undef SB
#undef BUFO
#undef STAGE
#undef LOADB
#undef WAITV
#undef COMPUTE

    // C/D layout: col = lane&15, row = (lane>>4)*4 + reg   [verified rounds 1-14]
    unsigned short* sp = spart + (size_t)kc * SFK;
    #pragma unroll
    for (int i = 0; i < 2; ++i) {
        #pragma unroll
        for (int nt = 0; nt < 7; ++nt) {
            const int c = nt * 16 + lr;
            #pragma unroll
            for (int r = 0; r < 4; ++r) {
                const int mm = m0 + w * 32 + i * 16 + lg * 4 + r;
                sp[(size_t)mm * CP + c] = f2bf(acc[i][nt][r]);
            }
        }
    }
}

// ---------------- fused tail: split-K sum + entropies + last-block finalize ----------------
__global__ __launch_bounds__(256) void ebl_tail(
    const unsigned short* __restrict__ spart, float* __restrict__ fpart,
    unsigned* __restrict__ cnt, float* __restrict__ out)
{
    __shared__ float Ss[32 * CP];
    __shared__ float massL[32];
    __shared__ float red[4];
    __shared__ int lastFlag;
    const int t = threadIdx.x;
    const int f = blockIdx.x;
    const size_t base = (size_t)f * 32 * CP;   // 3584 contiguous elements per partial

    for (int v = t; v < 32 * CP / 8; v += 256) {
        float s[8];
        #pragma unroll
        for (int j = 0; j < 8; ++j) s[j] = 0.f;
        for (int p = 0; p < NKC; ++p) {
            uint4 raw = *reinterpret_cast<const uint4*>(spart + (size_t)p * SFK + base + (size_t)v * 8);
            const unsigned short* u = reinterpret_cast<const unsigned short*>(&raw);
            #pragma unroll
            for (int j = 0; j < 8; ++j) s[j] += __uint_as_float((unsigned)u[j] << 16);
        }
        #pragma unroll
        for (int j = 0; j < 8; ++j) Ss[v * 8 + j] = s[j];
    }
    __syncthreads();
    if (t < 32) massL[t] = Ss[t * CP + CD] + EPSF;   // ones-column = bin mass (+EPS)
    __syncthreads();

    float a_int = 0.f, a_mix = 0.f;
    for (int idx = t; idx < 32 * CD; idx += 256) {
        const int k = idx / CD, c = idx - k * CD;
        const float cent = Ss[k * CP + c] / massL[k];
        a_int -= cent * logf(cent + EPSF) * massL[k];
    }
    for (int idx = t; idx < 31 * CD; idx += 256) {
        const int k = idx / CD, c = idx - k * CD;
        const float mix = 0.5f * (Ss[k * CP + c] / massL[k] + Ss[(k + 1) * CP + c] / massL[k + 1]);
        a_mix += mix * logf(mix + EPSF);
    }

    float part = a_int * (1.0f / (float)NS) + 0.5f * a_mix;
    #pragma unroll
    for (int off = 32; off > 0; off >>= 1) part += __shfl_down(part, off);
    if ((t & 63) == 0) red[t >> 6] = part;
    __syncthreads();

    if (t == 0) {
        fpart[f] = (red[0] + red[1]) + (red[2] + red[3]);
        __threadfence();                                   // release fpart[f] device-wide
        const unsigned ticket =
            __hip_atomic_fetch_add(cnt, 1u, __ATOMIC_ACQ_REL, __HIP_MEMORY_SCOPE_AGENT);
        lastFlag = (ticket == 63);                         // completion-count, no order assumption
    }
    __syncthreads();

    if (lastFlag && t < 64) {
        float v = __hip_atomic_load(&fpart[t], __ATOMIC_ACQUIRE, __HIP_MEMORY_SCOPE_AGENT);
        #pragma unroll
        for (int off = 32; off > 0; off >>= 1) v += __shfl_down(v, off);
        if (t == 0) out[0] = v;
    }
}

extern "C" void kernel_launch(void* const* d_in, const int* in_sizes, int n_in,
                              void* d_out, int out_size, void* d_ws, size_t ws_size,
                              hipStream_t stream)
{
    const float* mem = (const float*)d_in[0];
    const float* tp  = (const float*)d_in[1];
    float* out = (float*)d_out;

    const size_t bpBytes = (size_t)NGRP * CP * 8 * 2;    // 3,670,016 B

    unsigned short* Bp    = (unsigned short*)d_ws;
    unsigned short* spart = (unsigned short*)((char*)d_ws + bpBytes);
    float*          fpart = (float*)((char*)spart + (size_t)NKC * SFK * 2);
    unsigned*       cnt   = (unsigned*)(fpart + 64);

    ebl_prep<<<(NGRP * CP + 255) / 256, 256, 0, stream>>>(tp, Bp, cnt);
    dim3 grid(FKD / 64, NKC);                            // 32 x 32 = 1024 blocks, 128 thr
    ebl_gemm<<<grid, 128, 0, stream>>>(mem, Bp, spart);
    ebl_tail<<<64, 256, 0, stream>>>(spart, fpart, cnt, out);
}